// Round 14
// baseline (614.370 us; speedup 1.0000x reference)
//
#include <hip/hip_runtime.h>
#include <cstdint>
#include <cstddef>

// ---------------------------------------------------------------- types/helpers
typedef __attribute__((ext_vector_type(8))) short bfrag8;   // 8 bf16 = 4 VGPR (MFMA A/B frag)
typedef __attribute__((ext_vector_type(4))) float facc4;    // MFMA C/D frag

#define DEV static __device__ __forceinline__

DEV uint16_t f2b(float f){                       // f32 -> bf16, RNE
  uint32_t b = __builtin_bit_cast(uint32_t, f);
  return (uint16_t)((b + 0x7FFFu + ((b >> 16) & 1u)) >> 16);
}
DEV float b2f(uint16_t h){
  uint32_t b = ((uint32_t)h) << 16;
  return __builtin_bit_cast(float, b);
}
DEV void gload_lds16(const void* g, void* l){    // async global->LDS, 16B/lane
  __builtin_amdgcn_global_load_lds((const __attribute__((address_space(1))) unsigned int*)g,
                                   (__attribute__((address_space(3))) unsigned int*)l, 16, 0, 0);
}

#define NPAD   16384      // proj width (z|xconv|B|C), power-of-2 ld; dt handled by dt_fused
#define DI     4096
#define SCALEF 0.125f     // D_STATE^-0.5

// ---------------------------------------------------------------- fused cast: x, in_proj_w, out_proj_w -> bf16
__global__ __launch_bounds__(256) void cast3(
    const float* __restrict__ x, const float* __restrict__ w, const float* __restrict__ op,
    uint16_t* __restrict__ xb, uint16_t* __restrict__ wb, uint16_t* __restrict__ opb)
{
  const int i = blockIdx.x * 256 + threadIdx.x;
  const float* src; uint16_t* dst; int j;
  if (i < 2097152){ src = x; dst = xb; j = i; }
  else if (i < 10518528){ src = w; dst = wb; j = i - 2097152; }
  else if (i < 12615680){ src = op; dst = opb; j = i - 10518528; }
  else return;
  const float4 v = ((const float4*)src)[j];
  uint64_t q = (uint64_t)f2b(v.x) | ((uint64_t)f2b(v.y) << 16)
             | ((uint64_t)f2b(v.z) << 32) | ((uint64_t)f2b(v.w) << 48);
  ((uint64_t*)dst)[j] = q;
}

// ---------------------------------------------------------------- GEMM1: proj = x @ W^T (cols 0..16384)
// BM=BN=256, BK=64, 8 waves (2M x 4N), per-wave 128x64 C. 2 LDS buffers (128KB, 1 blk/CU).
// GRID = 1024 = exactly 4 generations (R13-proven: +14% MfmaUtil from tail removal).
// PANEL map: 16 panels x (16 mt x 4 nt); XCD-swizzle within 64-block panel.
__global__ __launch_bounds__(512, 2) void gemm_bt5(
    const uint16_t* __restrict__ A, const uint16_t* __restrict__ Bw,
    uint16_t* __restrict__ Cout)
{
  __shared__ __align__(16) uint16_t sA[2][256*64];
  __shared__ __align__(16) uint16_t sB[2][256*64];
  const int tid = threadIdx.x, lane = tid & 63, wave = tid >> 6;
  const int bid = blockIdx.x;
  const int pid = bid >> 6;
  const int r = bid & 63;
  const int rs = (r & 7) * 8 + (r >> 3);
  const int mt = rs >> 2;
  const int nt = (pid << 2) + (rs & 3);
  const int m0 = mt << 8, n0 = nt << 8;
  const int Krow = 2048, NT = 32;
  const int wm = wave >> 2, wn = wave & 3;

  const int sr = lane >> 3;
  const int slu = ((lane & 7) ^ sr) << 3;
  const uint16_t* aS = A  + (size_t)(m0 + wave*8 + sr) * Krow + slu;
  const uint16_t* bS = Bw + (size_t)(n0 + wave*8 + sr) * Krow + slu;

  const int l15 = lane & 15;
  const int q = lane >> 4;
  const int u0 = ((q)     ^ (l15 & 7)) << 3;
  const int u1 = ((q + 4) ^ (l15 & 7)) << 3;
  const int abase = (wm*128 + l15) << 6;       // + mi*1024 (mi 0..7)
  const int bbase = (wn*64  + l15) << 6;       // + ni*1024

  facc4 acc[8][4] = {};
  bfrag8 a0[8], b0[4], a1[8], b1[4];

#define STA(bs, tt, c) gload_lds16(aS + (size_t)((c)*64)*Krow + (tt)*64, &sA[bs][((c)*64 + wave*8) << 6])
#define STB(bs, tt, c) gload_lds16(bS + (size_t)((c)*64)*Krow + (tt)*64, &sB[bs][((c)*64 + wave*8) << 6])
#define STAGE8(bs, tt) do{ STB(bs,tt,0);STB(bs,tt,1);STB(bs,tt,2);STB(bs,tt,3); \
                           STA(bs,tt,0);STA(bs,tt,1);STA(bs,tt,2);STA(bs,tt,3); }while(0)

  STAGE8(0, 0);
  asm volatile("s_waitcnt vmcnt(0)" ::: "memory");
  asm volatile("s_barrier" ::: "memory");
  __builtin_amdgcn_sched_barrier(0);
  #pragma unroll
  for (int i = 0; i < 8; i++) a0[i] = *(const bfrag8*)&sA[0][abase + i*1024 + u0];
  #pragma unroll
  for (int i = 0; i < 4; i++) b0[i] = *(const bfrag8*)&sB[0][bbase + i*1024 + u0];

  #pragma unroll 1
  for (int t = 0; t < NT; ++t){
    const int c = t & 1;
    const bool st = (t + 1 < NT);
    const uint16_t* sa = sA[c];
    const uint16_t* sb = sB[c];
    if (st){ STAGE8(c ^ 1, t + 1); }
    #pragma unroll
    for (int i = 0; i < 8; i++) a1[i] = *(const bfrag8*)&sa[abase + i*1024 + u1];
    #pragma unroll
    for (int i = 0; i < 4; i++) b1[i] = *(const bfrag8*)&sb[bbase + i*1024 + u1];
    __builtin_amdgcn_sched_barrier(0);
    __builtin_amdgcn_s_setprio(1);
    #pragma unroll
    for (int mi = 0; mi < 8; mi++)
      #pragma unroll
      for (int ni = 0; ni < 4; ni++)
        acc[mi][ni] = __builtin_amdgcn_mfma_f32_16x16x32_bf16(a0[mi], b0[ni], acc[mi][ni], 0, 0, 0);
    __builtin_amdgcn_s_setprio(0);
    __builtin_amdgcn_sched_barrier(0);
    asm volatile("s_waitcnt lgkmcnt(0)" ::: "memory");
    if (st){
      asm volatile("s_waitcnt vmcnt(0)" ::: "memory");
      asm volatile("s_barrier" ::: "memory");
    }
    __builtin_amdgcn_sched_barrier(0);
    if (st){
      const uint16_t* na = sA[c ^ 1];
      const uint16_t* nb = sB[c ^ 1];
      #pragma unroll
      for (int i = 0; i < 8; i++) a0[i] = *(const bfrag8*)&na[abase + i*1024 + u0];
      #pragma unroll
      for (int i = 0; i < 4; i++) b0[i] = *(const bfrag8*)&nb[bbase + i*1024 + u0];
    }
    __builtin_amdgcn_sched_barrier(0);
    __builtin_amdgcn_s_setprio(1);
    #pragma unroll
    for (int mi = 0; mi < 8; mi++)
      #pragma unroll
      for (int ni = 0; ni < 4; ni++)
        acc[mi][ni] = __builtin_amdgcn_mfma_f32_16x16x32_bf16(a1[mi], b1[ni], acc[mi][ni], 0, 0, 0);
    __builtin_amdgcn_s_setprio(0);
    __builtin_amdgcn_sched_barrier(0);
  }
#undef STA
#undef STB
#undef STAGE8

  #pragma unroll
  for (int mi = 0; mi < 8; mi++)
    #pragma unroll
    for (int ni = 0; ni < 4; ni++)
      #pragma unroll
      for (int r2 = 0; r2 < 4; r2++){
        const int gm = m0 + wm*128 + mi*16 + (lane >> 4)*4 + r2;
        const int gn = n0 + wn*64 + ni*16 + l15;
        Cout[(size_t)gm * NPAD + gn] = f2b(acc[mi][ni][r2]);
      }
}

// ---------------------------------------------------------------- dt_fused: dtraw GEMM + softplus/clip/cumsum, all in one
// 16 blocks (one per (b,c) chunk) x 512 thr. GEMM: 256 rows x 64 h, K=2048, dbuf LDS,
// counted vmcnt(5) ring (5 gloads/wave/tile). dtraw stays in LDS f32; then two-pass
// segmented cumsum (8 l-segs x 64 h) writes dtb/cumb/ctotb. No dtraw HBM roundtrip.
__global__ __launch_bounds__(512) void dt_fused(
    const uint16_t* __restrict__ A, const uint16_t* __restrict__ Wdt,
    const float* __restrict__ A_log, const float* __restrict__ dt_bias,
    float* __restrict__ dtb, float* __restrict__ cumb, float* __restrict__ ctotb)
{
  __shared__ __align__(16) uint16_t sX[2][256*64];   // 64 KB (reused as f32 dtf after K-loop)
  __shared__ __align__(16) uint16_t sW[2][64*64];    // 16 KB
  __shared__ float sSeg[512];                        // seg partial sums [seg][h]
  const int tid = threadIdx.x, lane = tid & 63, wave = tid >> 6;
  const int cc = blockIdx.x;                 // chunk = b*8+c
  const int m0 = cc << 8;
  const int Krow = 2048, NT = 32;

  const int sr = lane >> 3;
  const int slu = ((lane & 7) ^ sr) << 3;
  const uint16_t* xS = A   + (size_t)(m0 + wave*8 + sr) * Krow + slu;
  const uint16_t* wS = Wdt + (size_t)(wave*8 + sr) * Krow + slu;

  const int l15 = lane & 15;
  const int q = lane >> 4;
  const int u0 = ((q)     ^ (l15 & 7)) << 3;
  const int u1 = ((q + 4) ^ (l15 & 7)) << 3;
  const int abase = (wave*32 + l15) << 6;    // + mi*1024 (mi 0,1)
  const int bbase = l15 << 6;                // + nf*1024 (nf 0..3)

  facc4 acc[2][4] = {};

#define SGX(bs, tt, c) gload_lds16(xS + (size_t)((c)*64)*Krow + (tt)*64, &sX[bs][((c)*64 + wave*8) << 6])
#define SGW(bs, tt)    gload_lds16(wS + (tt)*64, &sW[bs][(wave*8) << 6])
#define STG(bs, tt)    do{ SGX(bs,tt,0);SGX(bs,tt,1);SGX(bs,tt,2);SGX(bs,tt,3); SGW(bs,tt); }while(0)

  STG(0, 0);
  STG(1, 1);
  asm volatile("s_waitcnt vmcnt(5)" ::: "memory");   // tile0 complete, tile1 in flight
  asm volatile("s_barrier" ::: "memory");
  __builtin_amdgcn_sched_barrier(0);

  #pragma unroll 1
  for (int t = 0; t < NT; ++t){
    const int c = t & 1;
    const bool st  = (t + 1 < NT);
    const bool st2 = (t + 2 < NT);
    bfrag8 af[2][2], bf[2][4];
    #pragma unroll
    for (int mi = 0; mi < 2; mi++){
      af[0][mi] = *(const bfrag8*)&sX[c][abase + mi*1024 + u0];
      af[1][mi] = *(const bfrag8*)&sX[c][abase + mi*1024 + u1];
    }
    #pragma unroll
    for (int nf = 0; nf < 4; nf++){
      bf[0][nf] = *(const bfrag8*)&sW[c][bbase + nf*1024 + u0];
      bf[1][nf] = *(const bfrag8*)&sW[c][bbase + nf*1024 + u1];
    }
    asm volatile("s_waitcnt lgkmcnt(0)" ::: "memory");
    asm volatile("s_barrier" ::: "memory");           // all waves done reading buf c
    __builtin_amdgcn_sched_barrier(0);
    if (st2){ STG(c, t + 2); }                        // refill freed buffer
    #pragma unroll
    for (int ks = 0; ks < 2; ks++)
      #pragma unroll
      for (int mi = 0; mi < 2; mi++)
        #pragma unroll
        for (int nf = 0; nf < 4; nf++)
          acc[mi][nf] = __builtin_amdgcn_mfma_f32_16x16x32_bf16(af[ks][mi], bf[ks][nf], acc[mi][nf], 0, 0, 0);
    if (st){
      if (st2) asm volatile("s_waitcnt vmcnt(5)" ::: "memory");  // t+1 landed, t+2 in flight
      else     asm volatile("s_waitcnt vmcnt(0)" ::: "memory");
      asm volatile("s_barrier" ::: "memory");
      __builtin_amdgcn_sched_barrier(0);
    }
  }
#undef SGX
#undef SGW
#undef STG

  // dtraw -> LDS f32 (reuse sX region; K-loop reads all complete via final in-loop barrier)
  float* dtf = (float*)&sX[0][0];
  __syncthreads();
  #pragma unroll
  for (int mi = 0; mi < 2; mi++)
    #pragma unroll
    for (int nf = 0; nf < 4; nf++)
      #pragma unroll
      for (int r2 = 0; r2 < 4; r2++){
        const int l = wave*32 + mi*16 + (lane >> 4)*4 + r2;
        const int h = nf*16 + l15;
        dtf[l*64 + h] = acc[mi][nf][r2];
      }
  __syncthreads();

  // dt pipeline: thread = (seg = tid>>6 in [0,8), h = tid&63); each seg handles 32 l values
  {
    const int h = tid & 63;
    const int seg = tid >> 6;
    const int g = cc*64 + h;
    const float Aa = -__expf(A_log[h]);
    const float bias = dt_bias[h];
    float s = 0.f;
    #pragma unroll 1
    for (int k = 0; k < 32; k++){
      const int l = seg*32 + k;
      const float xr = dtf[l*64 + h] + bias;
      const float sp = (xr > 20.f) ? xr : log1pf(__expf(xr));
      const float dtv = fminf(fmaxf(sp, 1e-4f), 0.5f);
      dtb[g*256 + l] = dtv;
      const float inc = Aa * dtv;
      dtf[l*64 + h] = inc;        // overwrite with increment for pass B
      s += inc;
    }
    sSeg[seg*64 + h] = s;
    __syncthreads();
    float pref = 0.f;
    #pragma unroll
    for (int j = 0; j < 8; j++) if (j < seg) pref += sSeg[j*64 + h];
    float run = pref;
    #pragma unroll 1
    for (int k = 0; k < 32; k++){
      const int l = seg*32 + k;
      run += dtf[l*64 + h];
      cumb[g*256 + l] = run;
    }
    if (seg == 7) ctotb[g] = run;
  }
}

// ---------------------------------------------------------------- GEMM2: m97-class 128x128, 2 blocks/CU (f32 out)
__global__ __launch_bounds__(256, 2) void gemm97(
    const uint16_t* __restrict__ A, const uint16_t* __restrict__ Bw,
    float* __restrict__ Cout, int Ndim, int Krow)
{
  __shared__ __align__(16) uint16_t sA[2][128*64];
  __shared__ __align__(16) uint16_t sB[2][128*64];
  const int tid = threadIdx.x, lane = tid & 63, wave = tid >> 6;
  const int bid = blockIdx.x;
  const int xcd = bid & 7;
  const int idx = bid >> 3;                 // [0,64)
  const int mt = ((xcd & 3) << 3) + (idx & 7);
  const int nt = ((xcd >> 2) << 3) + (idx >> 3);
  const int m0 = mt << 7, n0 = nt << 7;
  const int wm = wave >> 1, wn = wave & 1;
  const int NT = Krow >> 6;

  const int sr = lane >> 3;
  const int slu = ((lane & 7) ^ sr) << 3;
  const uint16_t* aS = A  + (size_t)(m0 + wave*8 + sr) * Krow + slu;
  const uint16_t* bS = Bw + (size_t)(n0 + wave*8 + sr) * Krow + slu;

  const int l15 = lane & 15;
  const int q = lane >> 4;
  const int u0 = ((q)     ^ (l15 & 7)) << 3;
  const int u1 = ((q + 4) ^ (l15 & 7)) << 3;
  const int abase = (wm*64 + l15) << 6;     // + mi*1024
  const int bbase = (wn*64 + l15) << 6;     // + ni*1024

  facc4 acc[4][4] = {};

#define GA(bs, tt, c) gload_lds16(aS + (size_t)((c)*32)*Krow + (tt)*64, &sA[bs][((c)*32 + wave*8) << 6])
#define GB(bs, tt, c) gload_lds16(bS + (size_t)((c)*32)*Krow + (tt)*64, &sB[bs][((c)*32 + wave*8) << 6])
#define STAGE(bs, tt) do{ GA(bs,tt,0);GA(bs,tt,1);GA(bs,tt,2);GA(bs,tt,3); \
                          GB(bs,tt,0);GB(bs,tt,1);GB(bs,tt,2);GB(bs,tt,3); }while(0)

  STAGE(0, 0);
  asm volatile("s_waitcnt vmcnt(0)" ::: "memory");
  asm volatile("s_barrier" ::: "memory");
  __builtin_amdgcn_sched_barrier(0);

  #pragma unroll 1
  for (int t = 0; t < NT; ++t){
    const int c = t & 1;
    const bool st = (t + 1 < NT);
    const uint16_t* sa = sA[c];
    const uint16_t* sb = sB[c];
    if (st){ STAGE(c ^ 1, t + 1); }
    bfrag8 af[2][4], bf[2][4];
    #pragma unroll
    for (int mi = 0; mi < 4; mi++){
      af[0][mi] = *(const bfrag8*)&sa[abase + mi*1024 + u0];
      af[1][mi] = *(const bfrag8*)&sa[abase + mi*1024 + u1];
    }
    #pragma unroll
    for (int ni = 0; ni < 4; ni++){
      bf[0][ni] = *(const bfrag8*)&sb[bbase + ni*1024 + u0];
      bf[1][ni] = *(const bfrag8*)&sb[bbase + ni*1024 + u1];
    }
    __builtin_amdgcn_sched_barrier(0);
    __builtin_amdgcn_s_setprio(1);
    #pragma unroll
    for (int ks = 0; ks < 2; ks++)
      #pragma unroll
      for (int mi = 0; mi < 4; mi++)
        #pragma unroll
        for (int ni = 0; ni < 4; ni++)
          acc[mi][ni] = __builtin_amdgcn_mfma_f32_16x16x32_bf16(af[ks][mi], bf[ks][ni], acc[mi][ni], 0, 0, 0);
    __builtin_amdgcn_s_setprio(0);
    __builtin_amdgcn_sched_barrier(0);
    if (st){
      asm volatile("s_waitcnt vmcnt(0)" ::: "memory");
      asm volatile("s_barrier" ::: "memory");
      __builtin_amdgcn_sched_barrier(0);
    }
  }
#undef GA
#undef GB
#undef STAGE

  #pragma unroll
  for (int mi = 0; mi < 4; mi++)
    #pragma unroll
    for (int ni = 0; ni < 4; ni++)
      #pragma unroll
      for (int r = 0; r < 4; r++){
        const int gm = m0 + wm*64 + mi*16 + (lane >> 4)*4 + r;
        const int gn = n0 + wn*64 + ni*16 + l15;
        Cout[(size_t)gm * Ndim + gn] = acc[mi][ni][r];
      }
}

// ---------------------------------------------------------------- pass1: per (b,c,h) conv+SiLU fused, y_intra + delta_h
__global__ __launch_bounds__(256) void chunk_pass1(
    const uint16_t* __restrict__ projb, const float* __restrict__ conv_w,
    const float* __restrict__ dtb, const float* __restrict__ cumb,
    const float* __restrict__ ctotb, uint16_t* __restrict__ yvb, float* __restrict__ dh)
{
  __shared__ __align__(16) uint16_t sCc[256*64];   // C tile, [l][n] XOR-swz
  __shared__ __align__(16) uint16_t sBc[256*64];   // B tile, [l][n] XOR-swz
  __shared__ __align__(16) uint16_t sXT[64*256];   // (xconv*dt)^T  [p][l] swz u^(p&7)^(p>>3)
  __shared__ __align__(16) uint16_t sBT[64*256];   // (B*dte)^T  [n][l] same swz
  __shared__ __align__(16) uint16_t sS[4][64*32];  // per-wave S strip [i][j] swz
  __shared__ float sCum[256];
  __shared__ float sDt[256];
  __shared__ float sDte[256];

  const int tid = threadIdx.x, lane = tid & 63, wave = tid >> 6;
  const int bx = blockIdx.x;                // ((b*8+c)*64 + h)
  const int h = bx & 63;
  const int r0 = (bx >> 6) << 8;            // global row base b*2048 + c*256

  // stage Cc/Bc via global_load_lds, source-swizzled
  {
    const int Ccol = 12288 + h*64;
    const int Bcol = 8192 + h*64;
    const int sr = lane >> 3;
    const int lu = (lane & 7) ^ (sr & 7);
    const uint16_t* cS = projb + (size_t)(r0 + wave*64 + sr)*NPAD + Ccol + lu*8;
    const uint16_t* bS = projb + (size_t)(r0 + wave*64 + sr)*NPAD + Bcol + lu*8;
    uint16_t* cD = sCc + wave*4096;
    uint16_t* bD = sBc + wave*4096;
    #pragma unroll
    for (int i = 0; i < 8; i++){
      gload_lds16(cS + (size_t)(i*8)*NPAD, cD + i*512);
      gload_lds16(bS + (size_t)(i*8)*NPAD, bD + i*512);
    }
  }
  const float ctot = ctotb[bx];
  {
    const float cv = cumb[bx*256 + tid];
    sCum[tid] = cv;
    sDt[tid]  = dtb[bx*256 + tid];
    sDte[tid] = __expf(ctot - cv);          // decay_to_end
  }
  __syncthreads();

  // reg-scatter transposed tiles; x comes from fused depthwise conv(4)+SiLU
  {
    const int lsub = tid >> 3;              // 0..31
    const int p0 = (tid & 7) * 8;
    float wc[8][4];
    #pragma unroll
    for (int k = 0; k < 8; k++){
      const float4 ww = *(const float4*)(conv_w + (size_t)(h*64 + p0 + k)*4);
      wc[k][0]=ww.x; wc[k][1]=ww.y; wc[k][2]=ww.z; wc[k][3]=ww.w;
    }
    #pragma unroll
    for (int rep = 0; rep < 8; rep++){
      const int l = rep*32 + lsub;
      const float dtl = sDt[l];
      const float dte = sDte[l];
      // depthwise conv over global-time within batch
      float ca[8] = {0,0,0,0,0,0,0,0};
      const int tb = (r0 & 2047) + l;       // t within batch
      #pragma unroll
      for (int j = 0; j < 4; j++){
        if (tb - 3 + j >= 0){
          const bfrag8 px = *(const bfrag8*)(projb + (size_t)(r0 + l - 3 + j)*NPAD + DI + h*64 + p0);
          #pragma unroll
          for (int k = 0; k < 8; k++) ca[k] += b2f((uint16_t)px[k]) * wc[k][j];
        }
      }
      const bfrag8 vb = *(const bfrag8*)(projb + (size_t)(r0 + l)*NPAD + 8192 + h*64 + p0);
      const int usrc = l >> 3;
      const int lrem = l & 7;
      #pragma unroll
      for (int k = 0; k < 8; k++){
        const int p = p0 + k;
        const int phys = usrc ^ (p & 7) ^ (p >> 3);
        const float xv = ca[k] / (1.f + __expf(-ca[k]));   // SiLU
        sXT[p*256 + phys*8 + lrem] = f2b(xv * dtl);
        sBT[p*256 + phys*8 + lrem] = f2b(b2f((uint16_t)vb[k]) * dte);
      }
    }
  }
  __syncthreads();

  const int i0 = wave * 64;                 // this wave's i-strip
  facc4 yacc[4][4] = {};

  #pragma unroll 1
  for (int jt = 0; jt < 8; jt++){
    // S'[j,i] = B @ C^T  (swapped so repack is contiguous b64 writes)
    facc4 sacc[2][4] = {};
    #pragma unroll
    for (int ks = 0; ks < 2; ks++){
      bfrag8 aB[2], bC[4];
      #pragma unroll
      for (int jf = 0; jf < 2; jf++){
        const int j = jt*32 + jf*16 + (lane & 15);
        const int u = ks*4 + (lane >> 4);
        aB[jf] = *(const bfrag8*)(sBc + j*64 + ((u ^ (j & 7)) << 3));
      }
      #pragma unroll
      for (int f = 0; f < 4; f++){
        const int i = i0 + f*16 + (lane & 15);
        const int u = ks*4 + (lane >> 4);
        bC[f] = *(const bfrag8*)(sCc + i*64 + ((u ^ (i & 7)) << 3));
      }
      #pragma unroll
      for (int jf = 0; jf < 2; jf++)
        #pragma unroll
        for (int f = 0; f < 4; f++)
          sacc[jf][f] = __builtin_amdgcn_mfma_f32_16x16x32_bf16(aB[jf], bC[f], sacc[jf][f], 0, 0, 0);
    }
    // decay*SCALE, causal mask, pack bf16 -> per-wave S strip [i][j]
    #pragma unroll
    for (int jf = 0; jf < 2; jf++)
      #pragma unroll
      for (int f = 0; f < 4; f++){
        const int iloc = f*16 + (lane & 15);
        const float cumi = sCum[i0 + iloc];
        uint64_t pk = 0;
        #pragma unroll
        for (int r = 0; r < 4; r++){
          const int j = jt*32 + jf*16 + (lane >> 4)*4 + r;
          float v = 0.f;
          if (j <= i0 + iloc)
            v = sacc[jf][f][r] * SCALEF * __expf(cumi - sCum[j]);
          pk |= ((uint64_t)f2b(v)) << (16*r);
        }
        const int jl = jf*16 + (lane >> 4)*4;
        const int phys2 = (jl >> 3) ^ (iloc & 3);
        *(uint64_t*)(&sS[wave][iloc*32 + phys2*8 + (jl & 7)]) = pk;
      }
    // y_intra += S_strip @ xdt   (A from strip, B from sXT)
    bfrag8 bX[4];
    #pragma unroll
    for (int pf = 0; pf < 4; pf++){
      const int p = pf*16 + (lane & 15);
      const int u = jt*4 + (lane >> 4);
      bX[pf] = *(const bfrag8*)(sXT + p*256 + ((u ^ (p & 7) ^ (p >> 3)) << 3));
    }
    #pragma unroll
    for (int f = 0; f < 4; f++){
      const int iloc = f*16 + (lane & 15);
      const int phys2 = (lane >> 4) ^ (iloc & 3);
      const bfrag8 aS = *(const bfrag8*)(&sS[wave][iloc*32 + phys2*8]);
      #pragma unroll
      for (int pf = 0; pf < 4; pf++)
        yacc[f][pf] = __builtin_amdgcn_mfma_f32_16x16x32_bf16(aS, bX[pf], yacc[f][pf], 0, 0, 0);
    }
  }

  // delta_h[p,n] = sum_l (xconv*dt)[l,p] * (B*dte)[l,n]; wave owns p-strip wave*16
  facc4 dacc[4] = {};
  #pragma unroll
  for (int ks = 0; ks < 8; ks++){
    const int p = wave*16 + (lane & 15);
    const int u = ks*4 + (lane >> 4);
    const bfrag8 aX = *(const bfrag8*)(sXT + p*256 + ((u ^ (p & 7) ^ (p >> 3)) << 3));
    #pragma unroll
    for (int nf = 0; nf < 4; nf++){
      const int n = nf*16 + (lane & 15);
      const bfrag8 bB = *(const bfrag8*)(sBT + n*256 + ((u ^ (n & 7) ^ (n >> 3)) << 3));
      dacc[nf] = __builtin_amdgcn_mfma_f32_16x16x32_bf16(aX, bB, dacc[nf], 0, 0, 0);
    }
  }

  #pragma unroll
  for (int f = 0; f < 4; f++)
    #pragma unroll
    for (int pf = 0; pf < 4; pf++)
      #pragma unroll
      for (int r = 0; r < 4; r++){
        const int i = i0 + f*16 + (lane >> 4)*4 + r;
        const int p = pf*16 + (lane & 15);
        yvb[(size_t)(r0 + i)*DI + h*64 + p] = f2b(yacc[f][pf][r]);
      }
  #pragma unroll
  for (int nf = 0; nf < 4; nf++)
    #pragma unroll
    for (int r = 0; r < 4; r++){
      const int p = wave*16 + (lane >> 4)*4 + r;
      const int n = nf*16 + (lane & 15);
      dh[(size_t)bx*4096 + p*64 + n] = dacc[nf][r];
    }
}

// ---------------------------------------------------------------- cross-chunk state scan (8 steps)
__global__ __launch_bounds__(256) void scan_states(
    const float* __restrict__ dh, const float* __restrict__ ctotb, float* __restrict__ states)
{
  const int bh = blockIdx.x;                // b*64 + h
  const int b = bh >> 6, h = bh & 63;
  const int tid = threadIdx.x;
  float st[16];
  #pragma unroll
  for (int k = 0; k < 16; k++) st[k] = 0.f;
  for (int c = 0; c < 8; c++){
    const int g = (b*8 + c)*64 + h;
    const size_t base = (size_t)g * 4096;
    const float cd = __expf(ctotb[g]);
    #pragma unroll
    for (int k = 0; k < 4; k++){
      const int e = tid*4 + k*1024;
      float4 o; o.x = st[k*4]; o.y = st[k*4+1]; o.z = st[k*4+2]; o.w = st[k*4+3];
      *(float4*)(states + base + e) = o;    // state BEFORE chunk c
      const float4 d = *(const float4*)(dh + base + e);
      st[k*4]   = cd*st[k*4]   + d.x;
      st[k*4+1] = cd*st[k*4+1] + d.y;
      st[k*4+2] = cd*st[k*4+2] + d.z;
      st[k*4+3] = cd*st[k*4+3] + d.w;
    }
  }
}

// ---------------------------------------------------------------- pass2: y += exp(cum)*SCALE * C @ h^T  (bf16 RMW)
__global__ __launch_bounds__(256) void chunk_pass2(
    const uint16_t* __restrict__ projb, const float* __restrict__ states,
    const float* __restrict__ cumb, uint16_t* __restrict__ yvb)
{
  __shared__ __align__(16) uint16_t sCc[256*64];
  __shared__ __align__(16) uint16_t sH[64*64];    // [p][n] swz
  __shared__ float sCum[256];
  const int tid = threadIdx.x, lane = tid & 63, wave = tid >> 6;
  const int bx = blockIdx.x, h = bx & 63, r0 = (bx >> 6) << 8;
  {
    const int Ccol = 12288 + h*64;
    const int sr = lane >> 3;
    const int lu = (lane & 7) ^ (sr & 7);
    const uint16_t* cS = projb + (size_t)(r0 + wave*64 + sr)*NPAD + Ccol + lu*8;
    uint16_t* cD = sCc + wave*4096;
    #pragma unroll
    for (int i = 0; i < 8; i++) gload_lds16(cS + (size_t)(i*8)*NPAD, cD + i*512);
  }
  #pragma unroll
  for (int k = 0; k < 4; k++){
    const int e = tid*4 + k*1024;
    const float4 v = *(const float4*)(states + (size_t)bx*4096 + e);
    const int p = e >> 6, n0 = e & 63;
    const int phys = (n0 >> 3) ^ (p & 7);
    uint64_t pk = (uint64_t)f2b(v.x) | ((uint64_t)f2b(v.y) << 16)
                | ((uint64_t)f2b(v.z) << 32) | ((uint64_t)f2b(v.w) << 48);
    *(uint64_t*)(&sH[p*64 + phys*8 + (n0 & 7)]) = pk;
  }
  sCum[tid] = cumb[bx*256 + tid];
  __syncthreads();

  const int i0 = wave*64;
  facc4 acc[4][4] = {};
  #pragma unroll
  for (int ks = 0; ks < 2; ks++){
    bfrag8 aC[4], bH[4];
    #pragma unroll
    for (int f = 0; f < 4; f++){
      const int i = i0 + f*16 + (lane & 15);
      const int u = ks*4 + (lane >> 4);
      aC[f] = *(const bfrag8*)(sCc + i*64 + ((u ^ (i & 7)) << 3));
    }
    #pragma unroll
    for (int pf = 0; pf < 4; pf++){
      const int p = pf*16 + (lane & 15);
      const int u = ks*4 + (lane >> 4);
      bH[pf] = *(const bfrag8*)(sH + p*64 + ((u ^ (p & 7)) << 3));
    }
    #pragma unroll
    for (int f = 0; f < 4; f++)
      #pragma unroll
      for (int pf = 0; pf < 4; pf++)
        acc[f][pf] = __builtin_amdgcn_mfma_f32_16x16x32_bf16(aC[f], bH[pf], acc[f][pf], 0, 0, 0);
  }
  #pragma unroll
  for (int f = 0; f < 4; f++)
    #pragma unroll
    for (int r = 0; r < 4; r++){
      const int i = i0 + f*16 + (lane >> 4)*4 + r;
      const float sc = SCALEF * __expf(sCum[i]);
      #pragma unroll
      for (int pf = 0; pf < 4; pf++){
        const int p = pf*16 + (lane & 15);
        uint16_t* yp = yvb + (size_t)(r0 + i)*DI + h*64 + p;
        *yp = f2b(b2f(*yp) + acc[f][pf][r] * sc);
      }
    }
}

// ---------------------------------------------------------------- RMSNorm + SiLU(z) gate -> bf16
__global__ __launch_bounds__(256) void norm_gate(
    const uint16_t* __restrict__ yvb, const uint16_t* __restrict__ projb, uint16_t* __restrict__ yb)
{
  const int row = blockIdx.x, tid = threadIdx.x;
  float v[16];
  float ss = 0.f;
  #pragma unroll
  for (int k = 0; k < 2; k++){
    const bfrag8 y8 = *(const bfrag8*)(yvb + (size_t)row*DI + tid*8 + k*2048);
    #pragma unroll
    for (int j = 0; j < 8; j++){
      const float f = b2f((uint16_t)y8[j]);
      v[k*8+j] = f;
      ss += f*f;
    }
  }
  #pragma unroll
  for (int off = 32; off > 0; off >>= 1) ss += __shfl_down(ss, off);
  __shared__ float red[4];
  if ((tid & 63) == 0) red[tid >> 6] = ss;
  __syncthreads();
  const float inv = rsqrtf((red[0]+red[1]+red[2]+red[3]) * (1.f/4096.f) + 1.1920929e-07f);
  #pragma unroll
  for (int k = 0; k < 2; k++){
    const int e = tid*8 + k*2048;
    const bfrag8 z8 = *(const bfrag8*)(projb + (size_t)row*NPAD + e);
    uint16_t o[8];
    #pragma unroll
    for (int j = 0; j < 8; j++){
      const float z = b2f((uint16_t)z8[j]);
      const float g = z / (1.f + __expf(-z));
      o[j] = f2b(v[k*8+j] * inv * g);
    }
    uint4 pk;
    pk.x = (uint32_t)o[0] | ((uint32_t)o[1] << 16);
    pk.y = (uint32_t)o[2] | ((uint32_t)o[3] << 16);
    pk.z = (uint32_t)o[4] | ((uint32_t)o[5] << 16);
    pk.w = (uint32_t)o[6] | ((uint32_t)o[7] << 16);
    *(uint4*)(yb + (size_t)row*DI + e) = pk;
  }
}

// ---------------------------------------------------------------- launcher
extern "C" void kernel_launch(void* const* d_in, const int* in_sizes, int n_in,
                              void* d_out, int out_size, void* d_ws, size_t ws_size,
                              hipStream_t stream)
{
  (void)in_sizes; (void)n_in; (void)out_size; (void)ws_size;
  const float* x         = (const float*)d_in[0];
  const float* in_proj_w = (const float*)d_in[1];
  const float* conv_w    = (const float*)d_in[2];
  const float* A_log     = (const float*)d_in[3];
  const float* dt_bias   = (const float*)d_in[4];
  const float* out_proj_w= (const float*)d_in[5];
  float* out = (float*)d_out;

  char* ws = (char*)d_ws;
  uint16_t* xb    = (uint16_t*)(ws + 0);               // 4096x2048 bf16 = 16.8MB (dead after gemms)
  uint16_t* yvb   = (uint16_t*)(ws + 0);               // 4096x4096 bf16 = 33.5MB (overlaps xb + wb head)
  uint16_t* wb    = (uint16_t*)(ws + 16777216);        // 16448x2048 bf16 -> end 84,148,224 (dead after gemms)
  uint16_t* projb = (uint16_t*)(ws + 84148224);        // 4096x16384 bf16 -> end 218,365,952
  float* dtb      = (float*)(ws + 218365952);          // 1024x256 f32
  float* cumb     = (float*)(ws + 219414528);          // 1024x256 f32
  float* ctotb    = (float*)(ws + 220463104);          // 1024 f32
  uint16_t* yb    = (uint16_t*)(ws + 220467200);       // 4096x4096 bf16 -> 254,021,632
  float* dh       = (float*)(ws + 254021632);          // 1024x64x64 f32 -> 270,798,848
  float* states   = (float*)(ws + 270798848);          // 1024x64x64 f32 -> 287,576,064
  uint16_t* opb   = (uint16_t*)(ws + 287576064);       // 2048x4096 bf16 -> 304,353,280

  // fused casts (x, in_proj_w incl dt rows, out_proj_w)
  cast3<<<49280, 256, 0, stream>>>(x, in_proj_w, out_proj_w, xb, wb, opb);

  // in_proj GEMM (bf16 out, cols 0..16384): 16 panels x 64 blocks = 1024 = 4 exact generations
  gemm_bt5<<<1024, 512, 0, stream>>>(xb, wb, projb);
  // dt GEMM + softplus/cumsum fused: 16 blocks (1 per chunk), dtraw never leaves LDS
  dt_fused<<<16, 512, 0, stream>>>(xb, wb + (size_t)16384*2048, A_log, dt_bias, dtb, cumb, ctotb);

  chunk_pass1<<<1024, 256, 0, stream>>>(projb, conv_w, dtb, cumb, ctotb, yvb, dh);
  scan_states<<<128, 256, 0, stream>>>(dh, ctotb, states);
  chunk_pass2<<<1024, 256, 0, stream>>>(projb, states, cumb, yvb);
  norm_gate<<<4096, 256, 0, stream>>>(yvb, projb, yb);

  // out_proj GEMM: 128x128 tiles, XCD-square map, 512 blocks, 2/CU, f32 out
  gemm97<<<512, 256, 0, stream>>>(yb, opb, out, 2048, 4096);
}

// Round 15
// 580.878 us; speedup vs baseline: 1.0577x; 1.0577x over previous
//
#include <hip/hip_runtime.h>
#include <cstdint>
#include <cstddef>

// ---------------------------------------------------------------- types/helpers
typedef __attribute__((ext_vector_type(8))) short bfrag8;   // 8 bf16 = 4 VGPR (MFMA A/B frag)
typedef __attribute__((ext_vector_type(4))) float facc4;    // MFMA C/D frag

#define DEV static __device__ __forceinline__

DEV uint16_t f2b(float f){                       // f32 -> bf16, RNE
  uint32_t b = __builtin_bit_cast(uint32_t, f);
  return (uint16_t)((b + 0x7FFFu + ((b >> 16) & 1u)) >> 16);
}
DEV float b2f(uint16_t h){
  uint32_t b = ((uint32_t)h) << 16;
  return __builtin_bit_cast(float, b);
}
DEV void gload_lds16(const void* g, void* l){    // async global->LDS, 16B/lane
  __builtin_amdgcn_global_load_lds((const __attribute__((address_space(1))) unsigned int*)g,
                                   (__attribute__((address_space(3))) unsigned int*)l, 16, 0, 0);
}

#define NPAD   16384      // proj width (z|xconv|B|C), power-of-2 ld; dt handled by gemm_dt
#define DI     4096
#define SCALEF 0.125f     // D_STATE^-0.5

// ---------------------------------------------------------------- fused cast: x, in_proj_w, out_proj_w -> bf16
__global__ __launch_bounds__(256) void cast3(
    const float* __restrict__ x, const float* __restrict__ w, const float* __restrict__ op,
    uint16_t* __restrict__ xb, uint16_t* __restrict__ wb, uint16_t* __restrict__ opb)
{
  const int i = blockIdx.x * 256 + threadIdx.x;
  const float* src; uint16_t* dst; int j;
  if (i < 2097152){ src = x; dst = xb; j = i; }
  else if (i < 10518528){ src = w; dst = wb; j = i - 2097152; }
  else if (i < 12615680){ src = op; dst = opb; j = i - 10518528; }
  else return;
  const float4 v = ((const float4*)src)[j];
  uint64_t q = (uint64_t)f2b(v.x) | ((uint64_t)f2b(v.y) << 16)
             | ((uint64_t)f2b(v.z) << 32) | ((uint64_t)f2b(v.w) << 48);
  ((uint64_t*)dst)[j] = q;
}

// ---------------------------------------------------------------- GEMM1: proj = x @ W^T (cols 0..16384)
// BM=BN=256, BK=64, 8 waves (2M x 4N), per-wave 128x64 C. 2 LDS buffers (128KB, 1 blk/CU).
// GRID = 1024 = exactly 4 generations (R13-proven: +14% MfmaUtil from tail removal).
// PANEL map: 16 panels x (16 mt x 4 nt); XCD-swizzle within 64-block panel.
__global__ __launch_bounds__(512, 2) void gemm_bt5(
    const uint16_t* __restrict__ A, const uint16_t* __restrict__ Bw,
    uint16_t* __restrict__ Cout)
{
  __shared__ __align__(16) uint16_t sA[2][256*64];
  __shared__ __align__(16) uint16_t sB[2][256*64];
  const int tid = threadIdx.x, lane = tid & 63, wave = tid >> 6;
  const int bid = blockIdx.x;
  const int pid = bid >> 6;
  const int r = bid & 63;
  const int rs = (r & 7) * 8 + (r >> 3);
  const int mt = rs >> 2;
  const int nt = (pid << 2) + (rs & 3);
  const int m0 = mt << 8, n0 = nt << 8;
  const int Krow = 2048, NT = 32;
  const int wm = wave >> 2, wn = wave & 3;

  const int sr = lane >> 3;
  const int slu = ((lane & 7) ^ sr) << 3;
  const uint16_t* aS = A  + (size_t)(m0 + wave*8 + sr) * Krow + slu;
  const uint16_t* bS = Bw + (size_t)(n0 + wave*8 + sr) * Krow + slu;

  const int l15 = lane & 15;
  const int q = lane >> 4;
  const int u0 = ((q)     ^ (l15 & 7)) << 3;
  const int u1 = ((q + 4) ^ (l15 & 7)) << 3;
  const int abase = (wm*128 + l15) << 6;       // + mi*1024 (mi 0..7)
  const int bbase = (wn*64  + l15) << 6;       // + ni*1024

  facc4 acc[8][4] = {};
  bfrag8 a0[8], b0[4], a1[8], b1[4];

#define STA(bs, tt, c) gload_lds16(aS + (size_t)((c)*64)*Krow + (tt)*64, &sA[bs][((c)*64 + wave*8) << 6])
#define STB(bs, tt, c) gload_lds16(bS + (size_t)((c)*64)*Krow + (tt)*64, &sB[bs][((c)*64 + wave*8) << 6])
#define STAGE8(bs, tt) do{ STB(bs,tt,0);STB(bs,tt,1);STB(bs,tt,2);STB(bs,tt,3); \
                           STA(bs,tt,0);STA(bs,tt,1);STA(bs,tt,2);STA(bs,tt,3); }while(0)

  STAGE8(0, 0);
  asm volatile("s_waitcnt vmcnt(0)" ::: "memory");
  asm volatile("s_barrier" ::: "memory");
  __builtin_amdgcn_sched_barrier(0);
  #pragma unroll
  for (int i = 0; i < 8; i++) a0[i] = *(const bfrag8*)&sA[0][abase + i*1024 + u0];
  #pragma unroll
  for (int i = 0; i < 4; i++) b0[i] = *(const bfrag8*)&sB[0][bbase + i*1024 + u0];

  #pragma unroll 1
  for (int t = 0; t < NT; ++t){
    const int c = t & 1;
    const bool st = (t + 1 < NT);
    const uint16_t* sa = sA[c];
    const uint16_t* sb = sB[c];
    if (st){ STAGE8(c ^ 1, t + 1); }
    #pragma unroll
    for (int i = 0; i < 8; i++) a1[i] = *(const bfrag8*)&sa[abase + i*1024 + u1];
    #pragma unroll
    for (int i = 0; i < 4; i++) b1[i] = *(const bfrag8*)&sb[bbase + i*1024 + u1];
    __builtin_amdgcn_sched_barrier(0);
    __builtin_amdgcn_s_setprio(1);
    #pragma unroll
    for (int mi = 0; mi < 8; mi++)
      #pragma unroll
      for (int ni = 0; ni < 4; ni++)
        acc[mi][ni] = __builtin_amdgcn_mfma_f32_16x16x32_bf16(a0[mi], b0[ni], acc[mi][ni], 0, 0, 0);
    __builtin_amdgcn_s_setprio(0);
    __builtin_amdgcn_sched_barrier(0);
    asm volatile("s_waitcnt lgkmcnt(0)" ::: "memory");
    if (st){
      asm volatile("s_waitcnt vmcnt(0)" ::: "memory");
      asm volatile("s_barrier" ::: "memory");
    }
    __builtin_amdgcn_sched_barrier(0);
    if (st){
      const uint16_t* na = sA[c ^ 1];
      const uint16_t* nb = sB[c ^ 1];
      #pragma unroll
      for (int i = 0; i < 8; i++) a0[i] = *(const bfrag8*)&na[abase + i*1024 + u0];
      #pragma unroll
      for (int i = 0; i < 4; i++) b0[i] = *(const bfrag8*)&nb[bbase + i*1024 + u0];
    }
    __builtin_amdgcn_sched_barrier(0);
    __builtin_amdgcn_s_setprio(1);
    #pragma unroll
    for (int mi = 0; mi < 8; mi++)
      #pragma unroll
      for (int ni = 0; ni < 4; ni++)
        acc[mi][ni] = __builtin_amdgcn_mfma_f32_16x16x32_bf16(a1[mi], b1[ni], acc[mi][ni], 0, 0, 0);
    __builtin_amdgcn_s_setprio(0);
    __builtin_amdgcn_sched_barrier(0);
  }
#undef STA
#undef STB
#undef STAGE8

  #pragma unroll
  for (int mi = 0; mi < 8; mi++)
    #pragma unroll
    for (int ni = 0; ni < 4; ni++)
      #pragma unroll
      for (int r2 = 0; r2 < 4; r2++){
        const int gm = m0 + wm*128 + mi*16 + (lane >> 4)*4 + r2;
        const int gn = n0 + wn*64 + ni*16 + l15;
        Cout[(size_t)gm * NPAD + gn] = f2b(acc[mi][ni][r2]);
      }
}

// ---------------------------------------------------------------- gemm_dt: dt partials, K-split x8 for parallelism
// 1024 blocks = 128 m-blocks x 8 k-slices (4 blocks/CU; R14 lesson: 16 blocks = latency-bound).
// Block (mblk, kh): 32 rows x 64 h over K-slice kh*256..+256 (4 K-tiles). f32 partial out.
__global__ __launch_bounds__(256) void gemm_dt(
    const uint16_t* __restrict__ A, const uint16_t* __restrict__ Wdt, float* __restrict__ dtp)
{
  __shared__ __align__(16) uint16_t sX[32*64];   // 4 KB
  __shared__ __align__(16) uint16_t sW[64*64];   // 8 KB
  const int tid = threadIdx.x, lane = tid & 63, wave = tid >> 6;
  const int kh = blockIdx.x & 7;
  const int mblk = blockIdx.x >> 3;
  const int m0 = mblk << 5;
  const int kstart = kh << 8;
  const int wm = wave >> 1, wn = wave & 1;
  const int Krow = 2048;

  const int sr = lane >> 3;
  const int slu = ((lane & 7) ^ sr) << 3;
  const uint16_t* xS = A   + (size_t)(m0 + wave*8 + sr) * Krow + kstart + slu;
  const uint16_t* wS = Wdt + (size_t)(wave*8 + sr) * Krow + kstart + slu;

  const int l15 = lane & 15;
  const int q = lane >> 4;
  const int u0 = ((q)     ^ (l15 & 7)) << 3;
  const int u1 = ((q + 4) ^ (l15 & 7)) << 3;
  const int abase = (wm*16 + l15) << 6;
  const int bbase = (wn*32 + l15) << 6;          // + nf*1024

  facc4 acc[2] = {};

  #pragma unroll 1
  for (int t = 0; t < 4; ++t){
    gload_lds16(xS + t*64, &sX[(wave*8) << 6]);
    gload_lds16(wS + t*64, &sW[(wave*8) << 6]);
    gload_lds16(wS + (size_t)32*Krow + t*64, &sW[(32 + wave*8) << 6]);
    asm volatile("s_waitcnt vmcnt(0)" ::: "memory");
    asm volatile("s_barrier" ::: "memory");
    bfrag8 a0 = *(const bfrag8*)&sX[abase + u0];
    bfrag8 a1 = *(const bfrag8*)&sX[abase + u1];
    #pragma unroll
    for (int nf = 0; nf < 2; nf++){
      const bfrag8 b0 = *(const bfrag8*)&sW[bbase + nf*1024 + u0];
      const bfrag8 b1 = *(const bfrag8*)&sW[bbase + nf*1024 + u1];
      acc[nf] = __builtin_amdgcn_mfma_f32_16x16x32_bf16(a0, b0, acc[nf], 0, 0, 0);
      acc[nf] = __builtin_amdgcn_mfma_f32_16x16x32_bf16(a1, b1, acc[nf], 0, 0, 0);
    }
    asm volatile("s_waitcnt lgkmcnt(0)" ::: "memory");
    asm volatile("s_barrier" ::: "memory");
  }

  #pragma unroll
  for (int nf = 0; nf < 2; nf++)
    #pragma unroll
    for (int r = 0; r < 4; r++){
      const int gm = m0 + wm*16 + (lane >> 4)*4 + r;
      const int h = wn*32 + nf*16 + l15;
      dtp[(size_t)kh*262144 + gm*64 + h] = acc[nf][r];
    }
}

// ---------------------------------------------------------------- GEMM2: m97-class 128x128, 2 blocks/CU (f32 out)
__global__ __launch_bounds__(256, 2) void gemm97(
    const uint16_t* __restrict__ A, const uint16_t* __restrict__ Bw,
    float* __restrict__ Cout, int Ndim, int Krow)
{
  __shared__ __align__(16) uint16_t sA[2][128*64];
  __shared__ __align__(16) uint16_t sB[2][128*64];
  const int tid = threadIdx.x, lane = tid & 63, wave = tid >> 6;
  const int bid = blockIdx.x;
  const int xcd = bid & 7;
  const int idx = bid >> 3;                 // [0,64)
  const int mt = ((xcd & 3) << 3) + (idx & 7);
  const int nt = ((xcd >> 2) << 3) + (idx >> 3);
  const int m0 = mt << 7, n0 = nt << 7;
  const int wm = wave >> 1, wn = wave & 1;
  const int NT = Krow >> 6;

  const int sr = lane >> 3;
  const int slu = ((lane & 7) ^ sr) << 3;
  const uint16_t* aS = A  + (size_t)(m0 + wave*8 + sr) * Krow + slu;
  const uint16_t* bS = Bw + (size_t)(n0 + wave*8 + sr) * Krow + slu;

  const int l15 = lane & 15;
  const int q = lane >> 4;
  const int u0 = ((q)     ^ (l15 & 7)) << 3;
  const int u1 = ((q + 4) ^ (l15 & 7)) << 3;
  const int abase = (wm*64 + l15) << 6;     // + mi*1024
  const int bbase = (wn*64 + l15) << 6;     // + ni*1024

  facc4 acc[4][4] = {};

#define GA(bs, tt, c) gload_lds16(aS + (size_t)((c)*32)*Krow + (tt)*64, &sA[bs][((c)*32 + wave*8) << 6])
#define GB(bs, tt, c) gload_lds16(bS + (size_t)((c)*32)*Krow + (tt)*64, &sB[bs][((c)*32 + wave*8) << 6])
#define STAGE(bs, tt) do{ GA(bs,tt,0);GA(bs,tt,1);GA(bs,tt,2);GA(bs,tt,3); \
                          GB(bs,tt,0);GB(bs,tt,1);GB(bs,tt,2);GB(bs,tt,3); }while(0)

  STAGE(0, 0);
  asm volatile("s_waitcnt vmcnt(0)" ::: "memory");
  asm volatile("s_barrier" ::: "memory");
  __builtin_amdgcn_sched_barrier(0);

  #pragma unroll 1
  for (int t = 0; t < NT; ++t){
    const int c = t & 1;
    const bool st = (t + 1 < NT);
    const uint16_t* sa = sA[c];
    const uint16_t* sb = sB[c];
    if (st){ STAGE(c ^ 1, t + 1); }
    bfrag8 af[2][4], bf[2][4];
    #pragma unroll
    for (int mi = 0; mi < 4; mi++){
      af[0][mi] = *(const bfrag8*)&sa[abase + mi*1024 + u0];
      af[1][mi] = *(const bfrag8*)&sa[abase + mi*1024 + u1];
    }
    #pragma unroll
    for (int ni = 0; ni < 4; ni++){
      bf[0][ni] = *(const bfrag8*)&sb[bbase + ni*1024 + u0];
      bf[1][ni] = *(const bfrag8*)&sb[bbase + ni*1024 + u1];
    }
    __builtin_amdgcn_sched_barrier(0);
    __builtin_amdgcn_s_setprio(1);
    #pragma unroll
    for (int ks = 0; ks < 2; ks++)
      #pragma unroll
      for (int mi = 0; mi < 4; mi++)
        #pragma unroll
        for (int ni = 0; ni < 4; ni++)
          acc[mi][ni] = __builtin_amdgcn_mfma_f32_16x16x32_bf16(af[ks][mi], bf[ks][ni], acc[mi][ni], 0, 0, 0);
    __builtin_amdgcn_s_setprio(0);
    __builtin_amdgcn_sched_barrier(0);
    if (st){
      asm volatile("s_waitcnt vmcnt(0)" ::: "memory");
      asm volatile("s_barrier" ::: "memory");
      __builtin_amdgcn_sched_barrier(0);
    }
  }
#undef GA
#undef GB
#undef STAGE

  #pragma unroll
  for (int mi = 0; mi < 4; mi++)
    #pragma unroll
    for (int ni = 0; ni < 4; ni++)
      #pragma unroll
      for (int r = 0; r < 4; r++){
        const int gm = m0 + wm*64 + mi*16 + (lane >> 4)*4 + r;
        const int gn = n0 + wn*64 + ni*16 + l15;
        Cout[(size_t)gm * Ndim + gn] = acc[mi][ni][r];
      }
}

// ---------------------------------------------------------------- dt = clip(softplus(sum(dtp)+bias)), cumsum(A*dt)
__global__ __launch_bounds__(256) void dt_cum(
    const float* __restrict__ dtp, const float* __restrict__ A_log, const float* __restrict__ dt_bias,
    float* __restrict__ dtb, float* __restrict__ cumb, float* __restrict__ ctotb)
{
  const int g = blockIdx.x*4 + (threadIdx.x >> 6);   // (b*8+c)*64+h
  const int lane = threadIdx.x & 63;
  const int h = g & 63;
  const int r0 = (g >> 6) << 8;
  const float A = -__expf(A_log[h]);
  const float bias = dt_bias[h];
  float loc[4], s = 0.f;
  #pragma unroll
  for (int k = 0; k < 4; k++){
    const int l = lane*4 + k;
    float xr = bias;
    #pragma unroll
    for (int pp = 0; pp < 8; pp++)
      xr += dtp[(size_t)pp*262144 + (size_t)(r0 + l)*64 + h];
    const float sp = (xr > 20.f) ? xr : log1pf(__expf(xr));
    const float dt = fminf(fmaxf(sp, 1e-4f), 0.5f);
    dtb[g*256 + l] = dt;
    s += A * dt;
    loc[k] = s;
  }
  float run = s;
  #pragma unroll
  for (int off = 1; off < 64; off <<= 1){
    const float tmp = __shfl_up(run, off);
    if (lane >= off) run += tmp;
  }
  const float excl = run - s;
  #pragma unroll
  for (int k = 0; k < 4; k++) cumb[g*256 + lane*4 + k] = excl + loc[k];
  if (lane == 63) ctotb[g] = run;
}

// ---------------------------------------------------------------- pass1: per (b,c,h) conv+SiLU fused, y_intra + delta_h
__global__ __launch_bounds__(256) void chunk_pass1(
    const uint16_t* __restrict__ projb, const float* __restrict__ conv_w,
    const float* __restrict__ dtb, const float* __restrict__ cumb,
    const float* __restrict__ ctotb, uint16_t* __restrict__ yvb, float* __restrict__ dh)
{
  __shared__ __align__(16) uint16_t sCc[256*64];   // C tile, [l][n] XOR-swz
  __shared__ __align__(16) uint16_t sBc[256*64];   // B tile, [l][n] XOR-swz
  __shared__ __align__(16) uint16_t sXT[64*256];   // (xconv*dt)^T  [p][l] swz u^(p&7)^(p>>3)
  __shared__ __align__(16) uint16_t sBT[64*256];   // (B*dte)^T  [n][l] same swz
  __shared__ __align__(16) uint16_t sS[4][64*32];  // per-wave S strip [i][j] swz
  __shared__ float sCum[256];
  __shared__ float sDt[256];
  __shared__ float sDte[256];

  const int tid = threadIdx.x, lane = tid & 63, wave = tid >> 6;
  const int bx = blockIdx.x;                // ((b*8+c)*64 + h)
  const int h = bx & 63;
  const int r0 = (bx >> 6) << 8;            // global row base b*2048 + c*256

  // stage Cc/Bc via global_load_lds, source-swizzled
  {
    const int Ccol = 12288 + h*64;
    const int Bcol = 8192 + h*64;
    const int sr = lane >> 3;
    const int lu = (lane & 7) ^ (sr & 7);
    const uint16_t* cS = projb + (size_t)(r0 + wave*64 + sr)*NPAD + Ccol + lu*8;
    const uint16_t* bS = projb + (size_t)(r0 + wave*64 + sr)*NPAD + Bcol + lu*8;
    uint16_t* cD = sCc + wave*4096;
    uint16_t* bD = sBc + wave*4096;
    #pragma unroll
    for (int i = 0; i < 8; i++){
      gload_lds16(cS + (size_t)(i*8)*NPAD, cD + i*512);
      gload_lds16(bS + (size_t)(i*8)*NPAD, bD + i*512);
    }
  }
  const float ctot = ctotb[bx];
  {
    const float cv = cumb[bx*256 + tid];
    sCum[tid] = cv;
    sDt[tid]  = dtb[bx*256 + tid];
    sDte[tid] = __expf(ctot - cv);          // decay_to_end
  }
  __syncthreads();

  // reg-scatter transposed tiles; x comes from fused depthwise conv(4)+SiLU
  {
    const int lsub = tid >> 3;              // 0..31
    const int p0 = (tid & 7) * 8;
    float wc[8][4];
    #pragma unroll
    for (int k = 0; k < 8; k++){
      const float4 ww = *(const float4*)(conv_w + (size_t)(h*64 + p0 + k)*4);
      wc[k][0]=ww.x; wc[k][1]=ww.y; wc[k][2]=ww.z; wc[k][3]=ww.w;
    }
    #pragma unroll
    for (int rep = 0; rep < 8; rep++){
      const int l = rep*32 + lsub;
      const float dtl = sDt[l];
      const float dte = sDte[l];
      // depthwise conv over global-time within batch
      float ca[8] = {0,0,0,0,0,0,0,0};
      const int tb = (r0 & 2047) + l;       // t within batch
      #pragma unroll
      for (int j = 0; j < 4; j++){
        if (tb - 3 + j >= 0){
          const bfrag8 px = *(const bfrag8*)(projb + (size_t)(r0 + l - 3 + j)*NPAD + DI + h*64 + p0);
          #pragma unroll
          for (int k = 0; k < 8; k++) ca[k] += b2f((uint16_t)px[k]) * wc[k][j];
        }
      }
      const bfrag8 vb = *(const bfrag8*)(projb + (size_t)(r0 + l)*NPAD + 8192 + h*64 + p0);
      const int usrc = l >> 3;
      const int lrem = l & 7;
      #pragma unroll
      for (int k = 0; k < 8; k++){
        const int p = p0 + k;
        const int phys = usrc ^ (p & 7) ^ (p >> 3);
        const float xv = ca[k] / (1.f + __expf(-ca[k]));   // SiLU
        sXT[p*256 + phys*8 + lrem] = f2b(xv * dtl);
        sBT[p*256 + phys*8 + lrem] = f2b(b2f((uint16_t)vb[k]) * dte);
      }
    }
  }
  __syncthreads();

  const int i0 = wave * 64;                 // this wave's i-strip
  facc4 yacc[4][4] = {};

  #pragma unroll 1
  for (int jt = 0; jt < 8; jt++){
    // S'[j,i] = B @ C^T  (swapped so repack is contiguous b64 writes)
    facc4 sacc[2][4] = {};
    #pragma unroll
    for (int ks = 0; ks < 2; ks++){
      bfrag8 aB[2], bC[4];
      #pragma unroll
      for (int jf = 0; jf < 2; jf++){
        const int j = jt*32 + jf*16 + (lane & 15);
        const int u = ks*4 + (lane >> 4);
        aB[jf] = *(const bfrag8*)(sBc + j*64 + ((u ^ (j & 7)) << 3));
      }
      #pragma unroll
      for (int f = 0; f < 4; f++){
        const int i = i0 + f*16 + (lane & 15);
        const int u = ks*4 + (lane >> 4);
        bC[f] = *(const bfrag8*)(sCc + i*64 + ((u ^ (i & 7)) << 3));
      }
      #pragma unroll
      for (int jf = 0; jf < 2; jf++)
        #pragma unroll
        for (int f = 0; f < 4; f++)
          sacc[jf][f] = __builtin_amdgcn_mfma_f32_16x16x32_bf16(aB[jf], bC[f], sacc[jf][f], 0, 0, 0);
    }
    // decay*SCALE, causal mask, pack bf16 -> per-wave S strip [i][j]
    #pragma unroll
    for (int jf = 0; jf < 2; jf++)
      #pragma unroll
      for (int f = 0; f < 4; f++){
        const int iloc = f*16 + (lane & 15);
        const float cumi = sCum[i0 + iloc];
        uint64_t pk = 0;
        #pragma unroll
        for (int r = 0; r < 4; r++){
          const int j = jt*32 + jf*16 + (lane >> 4)*4 + r;
          float v = 0.f;
          if (j <= i0 + iloc)
            v = sacc[jf][f][r] * SCALEF * __expf(cumi - sCum[j]);
          pk |= ((uint64_t)f2b(v)) << (16*r);
        }
        const int jl = jf*16 + (lane >> 4)*4;
        const int phys2 = (jl >> 3) ^ (iloc & 3);
        *(uint64_t*)(&sS[wave][iloc*32 + phys2*8 + (jl & 7)]) = pk;
      }
    // y_intra += S_strip @ xdt   (A from strip, B from sXT)
    bfrag8 bX[4];
    #pragma unroll
    for (int pf = 0; pf < 4; pf++){
      const int p = pf*16 + (lane & 15);
      const int u = jt*4 + (lane >> 4);
      bX[pf] = *(const bfrag8*)(sXT + p*256 + ((u ^ (p & 7) ^ (p >> 3)) << 3));
    }
    #pragma unroll
    for (int f = 0; f < 4; f++){
      const int iloc = f*16 + (lane & 15);
      const int phys2 = (lane >> 4) ^ (iloc & 3);
      const bfrag8 aS = *(const bfrag8*)(&sS[wave][iloc*32 + phys2*8]);
      #pragma unroll
      for (int pf = 0; pf < 4; pf++)
        yacc[f][pf] = __builtin_amdgcn_mfma_f32_16x16x32_bf16(aS, bX[pf], yacc[f][pf], 0, 0, 0);
    }
  }

  // delta_h[p,n] = sum_l (xconv*dt)[l,p] * (B*dte)[l,n]; wave owns p-strip wave*16
  facc4 dacc[4] = {};
  #pragma unroll
  for (int ks = 0; ks < 8; ks++){
    const int p = wave*16 + (lane & 15);
    const int u = ks*4 + (lane >> 4);
    const bfrag8 aX = *(const bfrag8*)(sXT + p*256 + ((u ^ (p & 7) ^ (p >> 3)) << 3));
    #pragma unroll
    for (int nf = 0; nf < 4; nf++){
      const int n = nf*16 + (lane & 15);
      const bfrag8 bB = *(const bfrag8*)(sBT + n*256 + ((u ^ (n & 7) ^ (n >> 3)) << 3));
      dacc[nf] = __builtin_amdgcn_mfma_f32_16x16x32_bf16(aX, bB, dacc[nf], 0, 0, 0);
    }
  }

  #pragma unroll
  for (int f = 0; f < 4; f++)
    #pragma unroll
    for (int pf = 0; pf < 4; pf++)
      #pragma unroll
      for (int r = 0; r < 4; r++){
        const int i = i0 + f*16 + (lane >> 4)*4 + r;
        const int p = pf*16 + (lane & 15);
        yvb[(size_t)(r0 + i)*DI + h*64 + p] = f2b(yacc[f][pf][r]);
      }
  #pragma unroll
  for (int nf = 0; nf < 4; nf++)
    #pragma unroll
    for (int r = 0; r < 4; r++){
      const int p = wave*16 + (lane >> 4)*4 + r;
      const int n = nf*16 + (lane & 15);
      dh[(size_t)bx*4096 + p*64 + n] = dacc[nf][r];
    }
}

// ---------------------------------------------------------------- cross-chunk state scan (8 steps)
__global__ __launch_bounds__(256) void scan_states(
    const float* __restrict__ dh, const float* __restrict__ ctotb, float* __restrict__ states)
{
  const int bh = blockIdx.x;                // b*64 + h
  const int b = bh >> 6, h = bh & 63;
  const int tid = threadIdx.x;
  float st[16];
  #pragma unroll
  for (int k = 0; k < 16; k++) st[k] = 0.f;
  for (int c = 0; c < 8; c++){
    const int g = (b*8 + c)*64 + h;
    const size_t base = (size_t)g * 4096;
    const float cd = __expf(ctotb[g]);
    #pragma unroll
    for (int k = 0; k < 4; k++){
      const int e = tid*4 + k*1024;
      float4 o; o.x = st[k*4]; o.y = st[k*4+1]; o.z = st[k*4+2]; o.w = st[k*4+3];
      *(float4*)(states + base + e) = o;    // state BEFORE chunk c
      const float4 d = *(const float4*)(dh + base + e);
      st[k*4]   = cd*st[k*4]   + d.x;
      st[k*4+1] = cd*st[k*4+1] + d.y;
      st[k*4+2] = cd*st[k*4+2] + d.z;
      st[k*4+3] = cd*st[k*4+3] + d.w;
    }
  }
}

// ---------------------------------------------------------------- pass2: y += exp(cum)*SCALE * C @ h^T  (bf16 RMW)
__global__ __launch_bounds__(256) void chunk_pass2(
    const uint16_t* __restrict__ projb, const float* __restrict__ states,
    const float* __restrict__ cumb, uint16_t* __restrict__ yvb)
{
  __shared__ __align__(16) uint16_t sCc[256*64];
  __shared__ __align__(16) uint16_t sH[64*64];    // [p][n] swz
  __shared__ float sCum[256];
  const int tid = threadIdx.x, lane = tid & 63, wave = tid >> 6;
  const int bx = blockIdx.x, h = bx & 63, r0 = (bx >> 6) << 8;
  {
    const int Ccol = 12288 + h*64;
    const int sr = lane >> 3;
    const int lu = (lane & 7) ^ (sr & 7);
    const uint16_t* cS = projb + (size_t)(r0 + wave*64 + sr)*NPAD + Ccol + lu*8;
    uint16_t* cD = sCc + wave*4096;
    #pragma unroll
    for (int i = 0; i < 8; i++) gload_lds16(cS + (size_t)(i*8)*NPAD, cD + i*512);
  }
  #pragma unroll
  for (int k = 0; k < 4; k++){
    const int e = tid*4 + k*1024;
    const float4 v = *(const float4*)(states + (size_t)bx*4096 + e);
    const int p = e >> 6, n0 = e & 63;
    const int phys = (n0 >> 3) ^ (p & 7);
    uint64_t pk = (uint64_t)f2b(v.x) | ((uint64_t)f2b(v.y) << 16)
                | ((uint64_t)f2b(v.z) << 32) | ((uint64_t)f2b(v.w) << 48);
    *(uint64_t*)(&sH[p*64 + phys*8 + (n0 & 7)]) = pk;
  }
  sCum[tid] = cumb[bx*256 + tid];
  __syncthreads();

  const int i0 = wave*64;
  facc4 acc[4][4] = {};
  #pragma unroll
  for (int ks = 0; ks < 2; ks++){
    bfrag8 aC[4], bH[4];
    #pragma unroll
    for (int f = 0; f < 4; f++){
      const int i = i0 + f*16 + (lane & 15);
      const int u = ks*4 + (lane >> 4);
      aC[f] = *(const bfrag8*)(sCc + i*64 + ((u ^ (i & 7)) << 3));
    }
    #pragma unroll
    for (int pf = 0; pf < 4; pf++){
      const int p = pf*16 + (lane & 15);
      const int u = ks*4 + (lane >> 4);
      bH[pf] = *(const bfrag8*)(sH + p*64 + ((u ^ (p & 7)) << 3));
    }
    #pragma unroll
    for (int f = 0; f < 4; f++)
      #pragma unroll
      for (int pf = 0; pf < 4; pf++)
        acc[f][pf] = __builtin_amdgcn_mfma_f32_16x16x32_bf16(aC[f], bH[pf], acc[f][pf], 0, 0, 0);
  }
  #pragma unroll
  for (int f = 0; f < 4; f++)
    #pragma unroll
    for (int r = 0; r < 4; r++){
      const int i = i0 + f*16 + (lane >> 4)*4 + r;
      const float sc = SCALEF * __expf(sCum[i]);
      #pragma unroll
      for (int pf = 0; pf < 4; pf++){
        const int p = pf*16 + (lane & 15);
        uint16_t* yp = yvb + (size_t)(r0 + i)*DI + h*64 + p;
        *yp = f2b(b2f(*yp) + acc[f][pf][r] * sc);
      }
    }
}

// ---------------------------------------------------------------- RMSNorm + SiLU(z) gate -> bf16
__global__ __launch_bounds__(256) void norm_gate(
    const uint16_t* __restrict__ yvb, const uint16_t* __restrict__ projb, uint16_t* __restrict__ yb)
{
  const int row = blockIdx.x, tid = threadIdx.x;
  float v[16];
  float ss = 0.f;
  #pragma unroll
  for (int k = 0; k < 2; k++){
    const bfrag8 y8 = *(const bfrag8*)(yvb + (size_t)row*DI + tid*8 + k*2048);
    #pragma unroll
    for (int j = 0; j < 8; j++){
      const float f = b2f((uint16_t)y8[j]);
      v[k*8+j] = f;
      ss += f*f;
    }
  }
  #pragma unroll
  for (int off = 32; off > 0; off >>= 1) ss += __shfl_down(ss, off);
  __shared__ float red[4];
  if ((tid & 63) == 0) red[tid >> 6] = ss;
  __syncthreads();
  const float inv = rsqrtf((red[0]+red[1]+red[2]+red[3]) * (1.f/4096.f) + 1.1920929e-07f);
  #pragma unroll
  for (int k = 0; k < 2; k++){
    const int e = tid*8 + k*2048;
    const bfrag8 z8 = *(const bfrag8*)(projb + (size_t)row*NPAD + e);
    uint16_t o[8];
    #pragma unroll
    for (int j = 0; j < 8; j++){
      const float z = b2f((uint16_t)z8[j]);
      const float g = z / (1.f + __expf(-z));
      o[j] = f2b(v[k*8+j] * inv * g);
    }
    uint4 pk;
    pk.x = (uint32_t)o[0] | ((uint32_t)o[1] << 16);
    pk.y = (uint32_t)o[2] | ((uint32_t)o[3] << 16);
    pk.z = (uint32_t)o[4] | ((uint32_t)o[5] << 16);
    pk.w = (uint32_t)o[6] | ((uint32_t)o[7] << 16);
    *(uint4*)(yb + (size_t)row*DI + e) = pk;
  }
}

// ---------------------------------------------------------------- launcher
extern "C" void kernel_launch(void* const* d_in, const int* in_sizes, int n_in,
                              void* d_out, int out_size, void* d_ws, size_t ws_size,
                              hipStream_t stream)
{
  (void)in_sizes; (void)n_in; (void)out_size; (void)ws_size;
  const float* x         = (const float*)d_in[0];
  const float* in_proj_w = (const float*)d_in[1];
  const float* conv_w    = (const float*)d_in[2];
  const float* A_log     = (const float*)d_in[3];
  const float* dt_bias   = (const float*)d_in[4];
  const float* out_proj_w= (const float*)d_in[5];
  float* out = (float*)d_out;

  char* ws = (char*)d_ws;
  uint16_t* xb    = (uint16_t*)(ws + 0);               // 4096x2048 bf16 = 16.8MB (dead after gemms)
  uint16_t* yvb   = (uint16_t*)(ws + 0);               // 4096x4096 bf16 = 33.5MB (overlaps xb + wb head)
  uint16_t* wb    = (uint16_t*)(ws + 16777216);        // 16448x2048 bf16 -> end 84,148,224 (dead after gemms)
  uint16_t* projb = (uint16_t*)(ws + 84148224);        // 4096x16384 bf16 -> end 218,365,952
  float* dtp      = (float*)(ws + 218365952);          // 8 x 4096x64 f32 partials -> 226,754,560
  float* dtb      = (float*)(ws + 226754560);          // 1024x256 f32
  float* cumb     = (float*)(ws + 227803136);          // 1024x256 f32
  float* ctotb    = (float*)(ws + 228851712);          // 1024 f32
  uint16_t* yb    = (uint16_t*)(ws + 228855808);       // 4096x4096 bf16 -> 262,410,240
  float* dh       = (float*)(ws + 262410240);          // 1024x64x64 f32 -> 279,187,456
  float* states   = (float*)(ws + 279187456);          // 1024x64x64 f32 -> 295,964,672
  uint16_t* opb   = (uint16_t*)(ws + 295964672);       // 2048x4096 bf16 -> 312,741,888

  // fused casts (x, in_proj_w incl dt rows, out_proj_w)
  cast3<<<49280, 256, 0, stream>>>(x, in_proj_w, out_proj_w, xb, wb, opb);

  // in_proj GEMM (bf16 out, cols 0..16384): 16 panels x 64 blocks = 1024 = 4 exact generations
  gemm_bt5<<<1024, 512, 0, stream>>>(xb, wb, projb);
  // dt partial GEMM: 128 m-blocks x 8 k-slices = 1024 blocks (R14 lesson: parallelism, not fusion)
  gemm_dt<<<1024, 256, 0, stream>>>(xb, wb + (size_t)16384*2048, dtp);

  dt_cum<<<256, 256, 0, stream>>>(dtp, A_log, dt_bias, dtb, cumb, ctotb);
  chunk_pass1<<<1024, 256, 0, stream>>>(projb, conv_w, dtb, cumb, ctotb, yvb, dh);
  scan_states<<<128, 256, 0, stream>>>(dh, ctotb, states);
  chunk_pass2<<<1024, 256, 0, stream>>>(projb, states, cumb, yvb);
  norm_gate<<<4096, 256, 0, stream>>>(yvb, projb, yb);

  // out_proj GEMM: 128x128 tiles, XCD-square map, 512 blocks, 2/CU, f32 out
  gemm97<<<512, 256, 0, stream>>>(yb, opb, out, 2048, 4096);
}